// Round 12
// baseline (306.039 us; speedup 1.0000x reference)
//
#include <hip/hip_runtime.h>
#include <hip/hip_bf16.h>

#define NE 100
#define NB 4096
#define ND 256
#define NF 32
#define NH 16
#define NL 8
#define BT 256
#define RSTRIDE 140                 // ring row stride (floats); 140%32=12 spreads banks
#define SLOTF (16 * RSTRIDE)        // floats per half-tile slot (16 rows x 128 cols + pad)

typedef float    floatx4 __attribute__((ext_vector_type(4)));
typedef float    floatx2 __attribute__((ext_vector_type(2)));
typedef _Float16 half8   __attribute__((ext_vector_type(8)));

__device__ __forceinline__ float sigf(float a) {
    return __builtin_amdgcn_rcpf(1.0f + __expf(-a));
}

// Producer/consumer wave specialization:
//   waves 0-1: phase1 MLP happens on all threads; then producers run
//     swapped-operand mfma_f32_16x16x32_f16 (verified R9-R11) + sigmoid and
//     ds_write 16x128 half-tiles into a per-pair 2-slot LDS ring.
//   waves 2-3: consumers ds_read ring rows and issue full-512B-segment NT
//     stores -- their stream is nearly pure stores, so HBM stays saturated
//     while producer VALU runs concurrently (fixes R11's serial-pipe convoy).
// Sync: produced/consumed counters in LDS, acquire/release workgroup atomics.
__global__ __launch_bounds__(256, 2)
void bagae_pc(const float* __restrict__ x,
              const int* __restrict__ idx,
              const float* __restrict__ We0, const float* __restrict__ be0,
              const float* __restrict__ We1, const float* __restrict__ be1,
              const float* __restrict__ Wl,  const float* __restrict__ bl,
              const float* __restrict__ Wd0, const float* __restrict__ bd0,
              const float* __restrict__ Wd1, const float* __restrict__ bd1,
              const float* __restrict__ Wo,  const float* __restrict__ bo,
              float* __restrict__ out)
{
    __shared__ float sPool[4 * SLOTF];    // 35.8 KB ring (2 pairs x 2 slots); sA aliases front 16 KB
    __shared__ _Float16 sB[ND * NF];      // 16 KB Wo fragments (stays live)
    __shared__ float s_We0[NF * NH];
    __shared__ float s_We1[NH * NL];
    __shared__ float s_Wl [NL * NL];
    __shared__ float s_Wd0[NL * NH];
    __shared__ float s_Wd1[NH * NF];
    __shared__ float s_be0[NH], s_be1[NL], s_bl[NL], s_bd0[NH], s_bd1[NF];
    __shared__ int   s_idx[NF];
    __shared__ int   s_flags[4];          // [0..1]=produced per pair, [2..3]=consumed per pair

    _Float16* sA = reinterpret_cast<_Float16*>(sPool);   // 256x32 fp16 d1 frags = 16 KB

    const int tid = threadIdx.x;
    const int e   = blockIdx.y;
    const int b0  = blockIdx.x * BT;

    // ---- stage small per-estimator weights + init flags ----
    {
        const float* We0e = We0 + e * (NF * NH);
        const float* Wd1e = Wd1 + e * (NH * NF);
        for (int i = tid; i < NF * NH; i += 256) { s_We0[i] = We0e[i]; s_Wd1[i] = Wd1e[i]; }
        if (tid < NH * NL) { s_We1[tid] = We1[e * NH * NL + tid];
                             s_Wd0[tid] = Wd0[e * NL * NH + tid]; }
        if (tid < NL * NL) { s_Wl[tid]  = Wl [e * NL * NL + tid]; }
        if (tid < NF)      { s_idx[tid] = idx[e * NF + tid];
                             s_bd1[tid] = bd1[e * NF + tid]; }
        if (tid < NH)      { s_be0[tid] = be0[e * NH + tid];
                             s_bd0[tid] = bd0[e * NH + tid]; }
        if (tid < NL)      { s_be1[tid] = be1[e * NL + tid];
                             s_bl [tid] = bl [e * NL + tid]; }
        if (tid < 4)       { s_flags[tid] = 0; }
    }

    // ---- stage B = Wo_e column tid as fp16 fragments (unit t*64+l linear) ----
    {
        const float* Woe = Wo + (long)e * NF * ND;
        float wcol[NF];
        #pragma unroll
        for (int k = 0; k < NF; ++k) wcol[k] = Woe[k * ND + tid];   // coalesced
        const int ct = tid >> 4, c16 = tid & 15;
        #pragma unroll
        for (int kc = 0; kc < 4; ++kc) {
            half8 v;
            #pragma unroll
            for (int j = 0; j < 8; ++j) v[j] = (_Float16)wcol[kc * 8 + j];
            const int u = (ct * 4 + kc) * 16 + c16;
            *reinterpret_cast<half8*>(&sB[u * 8]) = v;
        }
    }
    __syncthreads();

    // ---- phase 1: per-row MLP chain -> d1[32] (relu) -> A fragments ----
    {
        const float* xrow = x + (long)(b0 + tid) * ND;

        float xg[NF];
        #pragma unroll
        for (int f = 0; f < NF; ++f) xg[f] = xrow[s_idx[f]];

        float h0[NH];
        #pragma unroll
        for (int h = 0; h < NH; ++h) h0[h] = s_be0[h];
        #pragma unroll
        for (int f = 0; f < NF; ++f) {
            #pragma unroll
            for (int h = 0; h < NH; ++h)
                h0[h] = fmaf(xg[f], s_We0[f * NH + h], h0[h]);
        }
        // no ReLU on h0

        float h1[NL];
        #pragma unroll
        for (int l = 0; l < NL; ++l) h1[l] = s_be1[l];
        #pragma unroll
        for (int h = 0; h < NH; ++h) {
            #pragma unroll
            for (int l = 0; l < NL; ++l)
                h1[l] = fmaf(h0[h], s_We1[h * NL + l], h1[l]);
        }
        #pragma unroll
        for (int l = 0; l < NL; ++l) h1[l] = fmaxf(h1[l], 0.0f);

        float zz[NL];
        #pragma unroll
        for (int m = 0; m < NL; ++m) zz[m] = s_bl[m];
        #pragma unroll
        for (int l = 0; l < NL; ++l) {
            #pragma unroll
            for (int m = 0; m < NL; ++m)
                zz[m] = fmaf(h1[l], s_Wl[l * NL + m], zz[m]);
        }
        #pragma unroll
        for (int m = 0; m < NL; ++m) zz[m] = fmaxf(zz[m], 0.0f);

        float d0[NH];
        #pragma unroll
        for (int h = 0; h < NH; ++h) d0[h] = s_bd0[h];
        #pragma unroll
        for (int l = 0; l < NL; ++l) {
            #pragma unroll
            for (int h = 0; h < NH; ++h)
                d0[h] = fmaf(zz[l], s_Wd0[l * NH + h], d0[h]);
        }
        // no ReLU on d0

        float d1[NF];
        #pragma unroll
        for (int f = 0; f < NF; ++f) d1[f] = s_bd1[f];
        #pragma unroll
        for (int h = 0; h < NH; ++h) {
            #pragma unroll
            for (int f = 0; f < NF; ++f)
                d1[f] = fmaf(d0[h], s_Wd1[h * NF + f], d1[f]);
        }

        const int t = tid >> 4, r16 = tid & 15;
        #pragma unroll
        for (int kc = 0; kc < 4; ++kc) {
            half8 v;
            #pragma unroll
            for (int j = 0; j < 8; ++j)
                v[j] = (_Float16)fmaxf(d1[kc * 8 + j], 0.0f);   // relu on d1
            const int u = (t * 4 + kc) * 16 + r16;
            *reinterpret_cast<half8*>(&sA[u * 8]) = v;
        }
    }
    __syncthreads();   // sA, sB, flags ready

    const int w   = tid >> 6;
    const int l   = tid & 63;
    const int r16 = l & 15;
    const int cq  = (l >> 4) * 4;

    // producers pull all fragments into registers BEFORE ring writes clobber sA
    half8 bfr[16], afr[8];
    if (w < 2) {
        #pragma unroll
        for (int ct = 0; ct < 16; ++ct)
            bfr[ct] = *reinterpret_cast<const half8*>(&sB[(ct * 64 + l) * 8]);
        #pragma unroll
        for (int i = 0; i < 8; ++i)
            afr[i] = *reinterpret_cast<const half8*>(&sA[((w * 8 + i) * 64 + l) * 8]);
    }
    __syncthreads();   // frags in regs everywhere; ring may be overwritten now

    if (w < 2) {
        // ---------------- producer: waves 0,1 ----------------
        const int p = w;
        for (int k = 0; k < 16; ++k) {         // 16 half-tiles (8 tiles x 2 col-halves)
            const int i = k >> 1;              // tile index within this producer
            const int h = k & 1;               // column half (cols h*128 .. +128)
            while (k - __hip_atomic_load(&s_flags[2 + p], __ATOMIC_ACQUIRE,
                                         __HIP_MEMORY_SCOPE_WORKGROUP) >= 2)
                __builtin_amdgcn_s_sleep(1);
            float* slot = &sPool[(p * 2 + (k & 1)) * SLOTF];
            #pragma unroll
            for (int c2 = 0; c2 < 8; ++c2) {
                const int ct = h * 8 + c2;
                floatx4 acc = *reinterpret_cast<const floatx4*>(bo + e * ND + ct * 16 + cq);
                // swapped: Wo-frag in A slot, d1-frag in B slot -> transposed D
                acc = __builtin_amdgcn_mfma_f32_16x16x32_f16(bfr[ct], afr[i], acc, 0, 0, 0);
                floatx4 o;
                o.x = sigf(acc[0]);
                o.y = sigf(acc[1]);
                o.z = sigf(acc[2]);
                o.w = sigf(acc[3]);
                *reinterpret_cast<floatx4*>(&slot[r16 * RSTRIDE + c2 * 16 + cq]) = o;
            }
            if (l == 0)
                __hip_atomic_store(&s_flags[p], k + 1, __ATOMIC_RELEASE,
                                   __HIP_MEMORY_SCOPE_WORKGROUP);
        }
    } else {
        // ---------------- consumer: waves 2,3 ----------------
        const int p = w - 2;
        for (int k = 0; k < 16; ++k) {
            const int t = p * 8 + (k >> 1);
            const int h = k & 1;
            while (__hip_atomic_load(&s_flags[p], __ATOMIC_ACQUIRE,
                                     __HIP_MEMORY_SCOPE_WORKGROUP) <= k)
                __builtin_amdgcn_s_sleep(1);
            const float* slot = &sPool[(p * 2 + (k & 1)) * SLOTF];
            floatx2 v[16];
            #pragma unroll
            for (int r = 0; r < 16; ++r)
                v[r] = *reinterpret_cast<const floatx2*>(&slot[r * RSTRIDE + 2 * l]);
            if (l == 0)   // release: lgkmcnt(0) drains this wave's ds_reads first
                __hip_atomic_store(&s_flags[2 + p], k + 1, __ATOMIC_RELEASE,
                                   __HIP_MEMORY_SCOPE_WORKGROUP);
            float* obase = out + ((long)e * NB + b0 + t * 16) * ND + h * 128 + 2 * l;
            #pragma unroll
            for (int r = 0; r < 16; ++r)   // 64 lanes x 8B = full 512B segments
                __builtin_nontemporal_store(v[r], reinterpret_cast<floatx2*>(obase + (long)r * ND));
        }
    }
}

extern "C" void kernel_launch(void* const* d_in, const int* in_sizes, int n_in,
                              void* d_out, int out_size, void* d_ws, size_t ws_size,
                              hipStream_t stream) {
    const float* x   = (const float*)d_in[0];
    const int*   idx = (const int*)  d_in[1];
    const float* We0 = (const float*)d_in[2];
    const float* be0 = (const float*)d_in[3];
    const float* We1 = (const float*)d_in[4];
    const float* be1 = (const float*)d_in[5];
    const float* Wl  = (const float*)d_in[6];
    const float* bl  = (const float*)d_in[7];
    const float* Wd0 = (const float*)d_in[8];
    const float* bd0 = (const float*)d_in[9];
    const float* Wd1 = (const float*)d_in[10];
    const float* bd1 = (const float*)d_in[11];
    const float* Wo  = (const float*)d_in[12];
    const float* bo  = (const float*)d_in[13];
    float* out = (float*)d_out;

    dim3 grid(NB / BT, NE);
    dim3 block(256);
    hipLaunchKernelGGL(bagae_pc, grid, block, 0, stream,
                       x, idx, We0, be0, We1, be1, Wl, bl,
                       Wd0, bd0, Wd1, bd1, Wo, bo, out);
}

// Round 14
// 123.663 us; speedup vs baseline: 2.4748x; 2.4748x over previous
//
#include <hip/hip_runtime.h>
#include <hip/hip_bf16.h>

#define NE 100
#define NB 4096
#define ND 256
#define NF 32
#define NH 16
#define NL 8
#define BT 256
#define HSTRIDE 132   // half-tile repack row stride (floats); conflict-free for b128 w / b64 r

typedef float    floatx4 __attribute__((ext_vector_type(4)));
typedef float    floatx2 __attribute__((ext_vector_type(2)));
typedef _Float16 half8   __attribute__((ext_vector_type(8)));

#define NLOG2E -1.44269504088896f

__device__ __forceinline__ float sig2(float a) {   // a = -log2e*x ; sigmoid(x)
    return __builtin_amdgcn_rcpf(1.0f + __builtin_amdgcn_exp2f(a));
}

// R11 structure (verified 119us) + two levers:
//  * repack half-tiles 16x128 so the pool (4 waves x 8.25KB = 33.8KB) aliases
//    BOTH dead fragment buffers -> total LDS ~40KB -> 4 blocks/CU (16 waves),
//    doubling TLP for store/VALU overlap. NT stores = 512B full-line segments.
//  * -log2(e) pre-folded into fp16 Wo staging + bias init -> sigmoid is
//    rcp(1+exp2(acc)), deleting the per-element multiply.
__global__ __launch_bounds__(256, 4)
void bagae_mfma(const float* __restrict__ x,
                const int* __restrict__ idx,
                const float* __restrict__ We0, const float* __restrict__ be0,
                const float* __restrict__ We1, const float* __restrict__ be1,
                const float* __restrict__ Wl,  const float* __restrict__ bl,
                const float* __restrict__ Wd0, const float* __restrict__ bd0,
                const float* __restrict__ Wd1, const float* __restrict__ bd1,
                const float* __restrict__ Wo,  const float* __restrict__ bo,
                float* __restrict__ out)
{
    // pool: 4 waves x 16 x HSTRIDE floats = 33,792B.
    // sA aliases floats [0, 4096) (16KB), sB aliases floats [4096, 8192) (16KB);
    // both dead after the frag->register load (barrier-separated).
    __shared__ float sPool[4 * 16 * HSTRIDE];
    __shared__ float s_We0[NF * NH];
    __shared__ float s_We1[NH * NL];
    __shared__ float s_Wl [NL * NL];
    __shared__ float s_Wd0[NL * NH];
    __shared__ float s_Wd1[NH * NF];
    __shared__ float s_be0[NH], s_be1[NL], s_bl[NL], s_bd0[NH], s_bd1[NF];
    __shared__ int   s_idx[NF];

    _Float16* sA = reinterpret_cast<_Float16*>(sPool);          // 256x32 fp16
    _Float16* sB = reinterpret_cast<_Float16*>(sPool) + BT * NF;// 256x32 fp16 (scaled)

    const int tid = threadIdx.x;
    const int e   = blockIdx.y;
    const int b0  = blockIdx.x * BT;

    // ---- stage small per-estimator weights ----
    {
        const float* We0e = We0 + e * (NF * NH);
        const float* Wd1e = Wd1 + e * (NH * NF);
        for (int i = tid; i < NF * NH; i += 256) { s_We0[i] = We0e[i]; s_Wd1[i] = Wd1e[i]; }
        if (tid < NH * NL) { s_We1[tid] = We1[e * NH * NL + tid];
                             s_Wd0[tid] = Wd0[e * NL * NH + tid]; }
        if (tid < NL * NL) { s_Wl[tid]  = Wl [e * NL * NL + tid]; }
        if (tid < NF)      { s_idx[tid] = idx[e * NF + tid];
                             s_bd1[tid] = bd1[e * NF + tid]; }
        if (tid < NH)      { s_be0[tid] = be0[e * NH + tid];
                             s_bd0[tid] = bd0[e * NH + tid]; }
        if (tid < NL)      { s_be1[tid] = be1[e * NL + tid];
                             s_bl [tid] = bl [e * NL + tid]; }
    }

    // ---- stage B = (-log2e * Wo_e) column tid as fp16 fragments ----
    // unit u(tile,kc,i16) = tile*64 + kc*16 + i16 (16B units); lane l of
    // tile t reads unit t*64+l -> linear, conflict-free.
    {
        const float* Woe = Wo + (long)e * NF * ND;
        float wcol[NF];
        #pragma unroll
        for (int k = 0; k < NF; ++k) wcol[k] = Woe[k * ND + tid];   // coalesced
        const int ct = tid >> 4, c16 = tid & 15;
        #pragma unroll
        for (int kc = 0; kc < 4; ++kc) {
            half8 v;
            #pragma unroll
            for (int j = 0; j < 8; ++j) v[j] = (_Float16)(wcol[kc * 8 + j] * NLOG2E);
            const int u = (ct * 4 + kc) * 16 + c16;
            *reinterpret_cast<half8*>(&sB[u * 8]) = v;
        }
    }
    __syncthreads();

    // ---- phase 1: per-row MLP chain -> d1[32] (relu) -> A fragments ----
    {
        const float* xrow = x + (long)(b0 + tid) * ND;

        float xg[NF];
        #pragma unroll
        for (int f = 0; f < NF; ++f) xg[f] = xrow[s_idx[f]];

        float h0[NH];
        #pragma unroll
        for (int h = 0; h < NH; ++h) h0[h] = s_be0[h];
        #pragma unroll
        for (int f = 0; f < NF; ++f) {
            #pragma unroll
            for (int h = 0; h < NH; ++h)
                h0[h] = fmaf(xg[f], s_We0[f * NH + h], h0[h]);
        }
        // no ReLU on h0

        float h1[NL];
        #pragma unroll
        for (int l = 0; l < NL; ++l) h1[l] = s_be1[l];
        #pragma unroll
        for (int h = 0; h < NH; ++h) {
            #pragma unroll
            for (int l = 0; l < NL; ++l)
                h1[l] = fmaf(h0[h], s_We1[h * NL + l], h1[l]);
        }
        #pragma unroll
        for (int l = 0; l < NL; ++l) h1[l] = fmaxf(h1[l], 0.0f);

        float zz[NL];
        #pragma unroll
        for (int m = 0; m < NL; ++m) zz[m] = s_bl[m];
        #pragma unroll
        for (int l = 0; l < NL; ++l) {
            #pragma unroll
            for (int m = 0; m < NL; ++m)
                zz[m] = fmaf(h1[l], s_Wl[l * NL + m], zz[m]);
        }
        #pragma unroll
        for (int m = 0; m < NL; ++m) zz[m] = fmaxf(zz[m], 0.0f);

        float d0[NH];
        #pragma unroll
        for (int h = 0; h < NH; ++h) d0[h] = s_bd0[h];
        #pragma unroll
        for (int l = 0; l < NL; ++l) {
            #pragma unroll
            for (int h = 0; h < NH; ++h)
                d0[h] = fmaf(zz[l], s_Wd0[l * NH + h], d0[h]);
        }
        // no ReLU on d0

        float d1[NF];
        #pragma unroll
        for (int f = 0; f < NF; ++f) d1[f] = s_bd1[f];
        #pragma unroll
        for (int h = 0; h < NH; ++h) {
            #pragma unroll
            for (int f = 0; f < NF; ++f)
                d1[f] = fmaf(d0[h], s_Wd1[h * NF + f], d1[f]);
        }

        const int t = tid >> 4, r16 = tid & 15;
        #pragma unroll
        for (int kc = 0; kc < 4; ++kc) {
            half8 v;
            #pragma unroll
            for (int j = 0; j < 8; ++j)
                v[j] = (_Float16)fmaxf(d1[kc * 8 + j], 0.0f);   // relu on d1
            const int u = (t * 4 + kc) * 16 + r16;
            *reinterpret_cast<half8*>(&sA[u * 8]) = v;
        }
    }
    __syncthreads();

    // ---- phase 2: frags -> registers, then the pool is repack space ----
    const int w   = tid >> 6;     // wave id: row-tiles [4w, 4w+4)
    const int l   = tid & 63;
    const int r16 = l & 15;       // output row within tile
    const int cq  = (l >> 4) * 4; // output col quad base within col-tile

    half8 bfr[16];
    #pragma unroll
    for (int ct = 0; ct < 16; ++ct)
        bfr[ct] = *reinterpret_cast<const half8*>(&sB[(ct * 64 + l) * 8]);
    half8 afr[4];
    #pragma unroll
    for (int i = 0; i < 4; ++i)
        afr[i] = *reinterpret_cast<const half8*>(&sA[((w * 4 + i) * 64 + l) * 8]);

    __syncthreads();   // frags in registers everywhere; pool free for repack

    // ---- MFMA + sigmoid -> half-tile repack -> 512B-segment NT stores ----
    {
        float* rep = &sPool[w * 16 * HSTRIDE];   // this wave's 16x128 buffer

        #pragma unroll
        for (int i = 0; i < 4; ++i) {
            const int rt = w * 4 + i;
            #pragma unroll
            for (int h = 0; h < 2; ++h) {
                // compute 16x128 half-tile, scatter to LDS
                #pragma unroll
                for (int c2 = 0; c2 < 8; ++c2) {
                    const int ct = h * 8 + c2;
                    floatx4 b4 = *reinterpret_cast<const floatx4*>(bo + e * ND + ct * 16 + cq);
                    floatx4 acc = b4 * NLOG2E;   // bias pre-scaled by -log2e
                    // swapped: Wo-frag in A slot, d1-frag in B slot -> transposed D
                    acc = __builtin_amdgcn_mfma_f32_16x16x32_f16(bfr[ct], afr[i], acc, 0, 0, 0);
                    floatx4 o;
                    o.x = sig2(acc[0]);
                    o.y = sig2(acc[1]);
                    o.z = sig2(acc[2]);
                    o.w = sig2(acc[3]);
                    *reinterpret_cast<floatx4*>(&rep[r16 * HSTRIDE + c2 * 16 + cq]) = o;
                }
                // read rows back, stream out: 64 lanes x 8B = full 512B segment
                float* obase = out + ((long)e * NB + b0 + rt * 16) * ND + h * 128 + 2 * l;
                #pragma unroll
                for (int r = 0; r < 16; ++r) {
                    floatx2 v = *reinterpret_cast<const floatx2*>(&rep[r * HSTRIDE + 2 * l]);
                    __builtin_nontemporal_store(v, reinterpret_cast<floatx2*>(obase + (long)r * ND));
                }
            }
        }
    }
}

extern "C" void kernel_launch(void* const* d_in, const int* in_sizes, int n_in,
                              void* d_out, int out_size, void* d_ws, size_t ws_size,
                              hipStream_t stream) {
    const float* x   = (const float*)d_in[0];
    const int*   idx = (const int*)  d_in[1];
    const float* We0 = (const float*)d_in[2];
    const float* be0 = (const float*)d_in[3];
    const float* We1 = (const float*)d_in[4];
    const float* be1 = (const float*)d_in[5];
    const float* Wl  = (const float*)d_in[6];
    const float* bl  = (const float*)d_in[7];
    const float* Wd0 = (const float*)d_in[8];
    const float* bd0 = (const float*)d_in[9];
    const float* Wd1 = (const float*)d_in[10];
    const float* bd1 = (const float*)d_in[11];
    const float* Wo  = (const float*)d_in[12];
    const float* bo  = (const float*)d_in[13];
    float* out = (float*)d_out;

    dim3 grid(NB / BT, NE);
    dim3 block(256);
    hipLaunchKernelGGL(bagae_mfma, grid, block, 0, stream,
                       x, idx, We0, be0, We1, be1, Wl, bl,
                       Wd0, bd0, Wd1, bd1, Wo, bo, out);
}

// Round 15
// 118.154 us; speedup vs baseline: 2.5902x; 1.0466x over previous
//
#include <hip/hip_runtime.h>
#include <hip/hip_bf16.h>

#define NE 100
#define NB 4096
#define ND 256
#define NF 32
#define NH 16
#define NL 8
#define BT 256
#define S_REP 264     // repack row stride in floats (264 mod 32 = 8 -> bank stagger)

typedef float    floatx4 __attribute__((ext_vector_type(4)));
typedef _Float16 half8   __attribute__((ext_vector_type(8)));

#define NLOG2E -1.44269504088896f

__device__ __forceinline__ float sig2(float a) {   // a = -log2e*x ; sigmoid(x)
    return __builtin_amdgcn_rcpf(1.0f + __builtin_amdgcn_exp2f(a));
}

// R11 structure (119us, full-1KB-row NT stores) with ONE resource fix:
// BOTH fragment buffers (sA and sB) alias the repack pool (they are dead
// after the frag->register load), cutting LDS from ~90KB (R11 ran 1
// block/CU!) to ~73.5KB -> 2 blocks/CU. Cross-block overlap fills the
// store-path idle gaps (phase1/staging of one block vs store drain of the
// other). Sigmoid via -log2e prefold + exp2 (validated R14).
__global__ __launch_bounds__(256, 2)
void bagae_mfma(const float* __restrict__ x,
                const int* __restrict__ idx,
                const float* __restrict__ We0, const float* __restrict__ be0,
                const float* __restrict__ We1, const float* __restrict__ be1,
                const float* __restrict__ Wl,  const float* __restrict__ bl,
                const float* __restrict__ Wd0, const float* __restrict__ bd0,
                const float* __restrict__ Wd1, const float* __restrict__ bd1,
                const float* __restrict__ Wo,  const float* __restrict__ bo,
                float* __restrict__ out)
{
    // pool: 4 waves x 16 x S_REP floats = 67,584B.
    // during staging: sA = bytes [0,16K), sB = bytes [16K,32K); both dead
    // after frag->reg load (barrier-separated from repack reuse).
    __shared__ float sPool[4 * 16 * S_REP];
    __shared__ float s_We0[NF * NH];
    __shared__ float s_We1[NH * NL];
    __shared__ float s_Wl [NL * NL];
    __shared__ float s_Wd0[NL * NH];
    __shared__ float s_Wd1[NH * NF];
    __shared__ float s_be0[NH], s_be1[NL], s_bl[NL], s_bd0[NH], s_bd1[NF];
    __shared__ int   s_idx[NF];

    _Float16* sA = reinterpret_cast<_Float16*>(sPool);           // 256x32 fp16 = 16KB
    _Float16* sB = reinterpret_cast<_Float16*>(sPool) + BT * NF; // 256x32 fp16 = 16KB

    const int tid = threadIdx.x;
    const int e   = blockIdx.y;
    const int b0  = blockIdx.x * BT;

    // ---- stage small per-estimator weights ----
    {
        const float* We0e = We0 + e * (NF * NH);
        const float* Wd1e = Wd1 + e * (NH * NF);
        for (int i = tid; i < NF * NH; i += 256) { s_We0[i] = We0e[i]; s_Wd1[i] = Wd1e[i]; }
        if (tid < NH * NL) { s_We1[tid] = We1[e * NH * NL + tid];
                             s_Wd0[tid] = Wd0[e * NL * NH + tid]; }
        if (tid < NL * NL) { s_Wl[tid]  = Wl [e * NL * NL + tid]; }
        if (tid < NF)      { s_idx[tid] = idx[e * NF + tid];
                             s_bd1[tid] = bd1[e * NF + tid]; }
        if (tid < NH)      { s_be0[tid] = be0[e * NH + tid];
                             s_bd0[tid] = bd0[e * NH + tid]; }
        if (tid < NL)      { s_be1[tid] = be1[e * NL + tid];
                             s_bl [tid] = bl [e * NL + tid]; }
    }

    // ---- stage B = (-log2e * Wo_e) column tid as fp16 fragments ----
    // unit u(tile,kc,i16) = tile*64 + kc*16 + i16 (16B units); lane l of
    // tile t reads unit t*64+l -> linear, conflict-free.
    {
        const float* Woe = Wo + (long)e * NF * ND;
        float wcol[NF];
        #pragma unroll
        for (int k = 0; k < NF; ++k) wcol[k] = Woe[k * ND + tid];   // coalesced
        const int ct = tid >> 4, c16 = tid & 15;
        #pragma unroll
        for (int kc = 0; kc < 4; ++kc) {
            half8 v;
            #pragma unroll
            for (int j = 0; j < 8; ++j) v[j] = (_Float16)(wcol[kc * 8 + j] * NLOG2E);
            const int u = (ct * 4 + kc) * 16 + c16;
            *reinterpret_cast<half8*>(&sB[u * 8]) = v;
        }
    }
    __syncthreads();

    // ---- phase 1: per-row MLP chain -> d1[32] (relu) -> A fragments ----
    {
        const float* xrow = x + (long)(b0 + tid) * ND;

        float xg[NF];
        #pragma unroll
        for (int f = 0; f < NF; ++f) xg[f] = xrow[s_idx[f]];

        float h0[NH];
        #pragma unroll
        for (int h = 0; h < NH; ++h) h0[h] = s_be0[h];
        #pragma unroll
        for (int f = 0; f < NF; ++f) {
            #pragma unroll
            for (int h = 0; h < NH; ++h)
                h0[h] = fmaf(xg[f], s_We0[f * NH + h], h0[h]);
        }
        // no ReLU on h0

        float h1[NL];
        #pragma unroll
        for (int l = 0; l < NL; ++l) h1[l] = s_be1[l];
        #pragma unroll
        for (int h = 0; h < NH; ++h) {
            #pragma unroll
            for (int l = 0; l < NL; ++l)
                h1[l] = fmaf(h0[h], s_We1[h * NL + l], h1[l]);
        }
        #pragma unroll
        for (int l = 0; l < NL; ++l) h1[l] = fmaxf(h1[l], 0.0f);

        float zz[NL];
        #pragma unroll
        for (int m = 0; m < NL; ++m) zz[m] = s_bl[m];
        #pragma unroll
        for (int l = 0; l < NL; ++l) {
            #pragma unroll
            for (int m = 0; m < NL; ++m)
                zz[m] = fmaf(h1[l], s_Wl[l * NL + m], zz[m]);
        }
        #pragma unroll
        for (int m = 0; m < NL; ++m) zz[m] = fmaxf(zz[m], 0.0f);

        float d0[NH];
        #pragma unroll
        for (int h = 0; h < NH; ++h) d0[h] = s_bd0[h];
        #pragma unroll
        for (int l = 0; l < NL; ++l) {
            #pragma unroll
            for (int h = 0; h < NH; ++h)
                d0[h] = fmaf(zz[l], s_Wd0[l * NH + h], d0[h]);
        }
        // no ReLU on d0

        float d1[NF];
        #pragma unroll
        for (int f = 0; f < NF; ++f) d1[f] = s_bd1[f];
        #pragma unroll
        for (int h = 0; h < NH; ++h) {
            #pragma unroll
            for (int f = 0; f < NF; ++f)
                d1[f] = fmaf(d0[h], s_Wd1[h * NF + f], d1[f]);
        }

        const int t = tid >> 4, r16 = tid & 15;
        #pragma unroll
        for (int kc = 0; kc < 4; ++kc) {
            half8 v;
            #pragma unroll
            for (int j = 0; j < 8; ++j)
                v[j] = (_Float16)fmaxf(d1[kc * 8 + j], 0.0f);   // relu on d1
            const int u = (t * 4 + kc) * 16 + r16;
            *reinterpret_cast<half8*>(&sA[u * 8]) = v;
        }
    }
    __syncthreads();

    // ---- phase 2: frags -> registers, then the pool is repack space ----
    const int w   = tid >> 6;     // wave id: row-tiles [4w, 4w+4)
    const int l   = tid & 63;
    const int r16 = l & 15;       // output row within tile
    const int cq  = (l >> 4) * 4; // output col quad base within col-tile

    half8 bfr[16];
    #pragma unroll
    for (int ct = 0; ct < 16; ++ct)
        bfr[ct] = *reinterpret_cast<const half8*>(&sB[(ct * 64 + l) * 8]);
    half8 afr[4];
    #pragma unroll
    for (int i = 0; i < 4; ++i)
        afr[i] = *reinterpret_cast<const half8*>(&sA[((w * 4 + i) * 64 + l) * 8]);

    __syncthreads();   // frags in registers everywhere; pool free for repack

    // ---- MFMA + sigmoid -> per-wave repack -> full-1KB-row NT stores ----
    {
        float* rep = &sPool[w * 16 * S_REP];   // this wave's 16x256 tile (padded)

        #pragma unroll
        for (int i = 0; i < 4; ++i) {
            const int rt = w * 4 + i;

            // compute & scatter one 16x256 row-tile into LDS
            #pragma unroll
            for (int ct = 0; ct < 16; ++ct) {
                floatx4 b4 = *reinterpret_cast<const floatx4*>(bo + e * ND + ct * 16 + cq);
                floatx4 acc = b4 * NLOG2E;   // bias pre-scaled by -log2e
                // swapped: Wo-frag in A slot, d1-frag in B slot -> transposed D
                acc = __builtin_amdgcn_mfma_f32_16x16x32_f16(bfr[ct], afr[i], acc, 0, 0, 0);
                floatx4 o;
                o.x = sig2(acc[0]);
                o.y = sig2(acc[1]);
                o.z = sig2(acc[2]);
                o.w = sig2(acc[3]);
                *reinterpret_cast<floatx4*>(&rep[r16 * S_REP + ct * 16 + cq]) = o;
            }

            // read rows back, stream out: one full 1KB row per instruction
            float* obase = out + ((long)e * NB + b0 + rt * 16) * ND + 4 * l;
            #pragma unroll
            for (int r = 0; r < 16; ++r) {
                floatx4 v = *reinterpret_cast<const floatx4*>(&rep[r * S_REP + 4 * l]);
                __builtin_nontemporal_store(v, reinterpret_cast<floatx4*>(obase + (long)r * ND));
            }
        }
    }
}

extern "C" void kernel_launch(void* const* d_in, const int* in_sizes, int n_in,
                              void* d_out, int out_size, void* d_ws, size_t ws_size,
                              hipStream_t stream) {
    const float* x   = (const float*)d_in[0];
    const int*   idx = (const int*)  d_in[1];
    const float* We0 = (const float*)d_in[2];
    const float* be0 = (const float*)d_in[3];
    const float* We1 = (const float*)d_in[4];
    const float* be1 = (const float*)d_in[5];
    const float* Wl  = (const float*)d_in[6];
    const float* bl  = (const float*)d_in[7];
    const float* Wd0 = (const float*)d_in[8];
    const float* bd0 = (const float*)d_in[9];
    const float* Wd1 = (const float*)d_in[10];
    const float* bd1 = (const float*)d_in[11];
    const float* Wo  = (const float*)d_in[12];
    const float* bo  = (const float*)d_in[13];
    float* out = (float*)d_out;

    dim3 grid(NB / BT, NE);
    dim3 block(256);
    hipLaunchKernelGGL(bagae_mfma, grid, block, 0, stream,
                       x, idx, We0, be0, We1, be1, Wl, bl,
                       Wd0, bd0, Wd1, bd1, Wo, bo, out);
}

// Round 16
// 115.521 us; speedup vs baseline: 2.6492x; 1.0228x over previous
//
#include <hip/hip_runtime.h>
#include <hip/hip_bf16.h>

#define NE 100
#define NB 4096
#define ND 256
#define NF 32
#define NH 16
#define NL 8
#define BT 256
#define S_REP 264     // repack row stride in floats (264 mod 32 = 8 -> bank stagger)

typedef float    floatx4 __attribute__((ext_vector_type(4)));
typedef _Float16 half8   __attribute__((ext_vector_type(8)));

#define NLOG2E -1.44269504088896f

__device__ __forceinline__ float sig2(float a) {   // a = -log2e*x ; sigmoid(x)
    return __builtin_amdgcn_rcpf(1.0f + __builtin_amdgcn_exp2f(a));
}

// R15 base (118us) + row-granular software pipeline in phase 2:
// tile i's compute (MFMA+sigmoid+ds_write, one ct-quad) is interleaved
// BETWEEN consecutive 1KB row-stores of tile i-1 (rows in 16 VGPR quads).
// Store issue is spread evenly through the instruction stream -> store
// queue stays fed (breaks the barrier-aligned all-wave store-burst convoy
// that made pipes run serially: 68us stores + 44us compute ~= 118 serial).
// Hot loop has ZERO vmem loads (bias pre-scaled into LDS) so no vmcnt wait
// couples store retirement into compute.
__global__ __launch_bounds__(256, 2)
void bagae_mfma(const float* __restrict__ x,
                const int* __restrict__ idx,
                const float* __restrict__ We0, const float* __restrict__ be0,
                const float* __restrict__ We1, const float* __restrict__ be1,
                const float* __restrict__ Wl,  const float* __restrict__ bl,
                const float* __restrict__ Wd0, const float* __restrict__ bd0,
                const float* __restrict__ Wd1, const float* __restrict__ bd1,
                const float* __restrict__ Wo,  const float* __restrict__ bo,
                float* __restrict__ out)
{
    // pool: 4 waves x 16 x S_REP floats = 67,584B.
    // during staging: sA = bytes [0,16K), sB = bytes [16K,32K); both dead
    // after frag->reg load (barrier-separated from repack reuse).
    __shared__ float sPool[4 * 16 * S_REP];
    __shared__ float sBias[ND];          // -log2e * bo_e
    __shared__ float s_We0[NF * NH];
    __shared__ float s_We1[NH * NL];
    __shared__ float s_Wl [NL * NL];
    __shared__ float s_Wd0[NL * NH];
    __shared__ float s_Wd1[NH * NF];
    __shared__ float s_be0[NH], s_be1[NL], s_bl[NL], s_bd0[NH], s_bd1[NF];
    __shared__ int   s_idx[NF];

    _Float16* sA = reinterpret_cast<_Float16*>(sPool);           // 256x32 fp16 = 16KB
    _Float16* sB = reinterpret_cast<_Float16*>(sPool) + BT * NF; // 256x32 fp16 = 16KB

    const int tid = threadIdx.x;
    const int e   = blockIdx.y;
    const int b0  = blockIdx.x * BT;

    // ---- stage small per-estimator weights + scaled output bias ----
    {
        const float* We0e = We0 + e * (NF * NH);
        const float* Wd1e = Wd1 + e * (NH * NF);
        for (int i = tid; i < NF * NH; i += 256) { s_We0[i] = We0e[i]; s_Wd1[i] = Wd1e[i]; }
        sBias[tid] = bo[e * ND + tid] * NLOG2E;
        if (tid < NH * NL) { s_We1[tid] = We1[e * NH * NL + tid];
                             s_Wd0[tid] = Wd0[e * NL * NH + tid]; }
        if (tid < NL * NL) { s_Wl[tid]  = Wl [e * NL * NL + tid]; }
        if (tid < NF)      { s_idx[tid] = idx[e * NF + tid];
                             s_bd1[tid] = bd1[e * NF + tid]; }
        if (tid < NH)      { s_be0[tid] = be0[e * NH + tid];
                             s_bd0[tid] = bd0[e * NH + tid]; }
        if (tid < NL)      { s_be1[tid] = be1[e * NL + tid];
                             s_bl [tid] = bl [e * NL + tid]; }
    }

    // ---- stage B = (-log2e * Wo_e) column tid as fp16 fragments ----
    // unit u(tile,kc,i16) = tile*64 + kc*16 + i16 (16B units); lane l of
    // tile t reads unit t*64+l -> linear, conflict-free.
    {
        const float* Woe = Wo + (long)e * NF * ND;
        float wcol[NF];
        #pragma unroll
        for (int k = 0; k < NF; ++k) wcol[k] = Woe[k * ND + tid];   // coalesced
        const int ct = tid >> 4, c16 = tid & 15;
        #pragma unroll
        for (int kc = 0; kc < 4; ++kc) {
            half8 v;
            #pragma unroll
            for (int j = 0; j < 8; ++j) v[j] = (_Float16)(wcol[kc * 8 + j] * NLOG2E);
            const int u = (ct * 4 + kc) * 16 + c16;
            *reinterpret_cast<half8*>(&sB[u * 8]) = v;
        }
    }
    __syncthreads();

    // ---- phase 1: per-row MLP chain -> d1[32] (relu) -> A fragments ----
    {
        const float* xrow = x + (long)(b0 + tid) * ND;

        float xg[NF];
        #pragma unroll
        for (int f = 0; f < NF; ++f) xg[f] = xrow[s_idx[f]];

        float h0[NH];
        #pragma unroll
        for (int h = 0; h < NH; ++h) h0[h] = s_be0[h];
        #pragma unroll
        for (int f = 0; f < NF; ++f) {
            #pragma unroll
            for (int h = 0; h < NH; ++h)
                h0[h] = fmaf(xg[f], s_We0[f * NH + h], h0[h]);
        }
        // no ReLU on h0

        float h1[NL];
        #pragma unroll
        for (int l = 0; l < NL; ++l) h1[l] = s_be1[l];
        #pragma unroll
        for (int h = 0; h < NH; ++h) {
            #pragma unroll
            for (int l = 0; l < NL; ++l)
                h1[l] = fmaf(h0[h], s_We1[h * NL + l], h1[l]);
        }
        #pragma unroll
        for (int l = 0; l < NL; ++l) h1[l] = fmaxf(h1[l], 0.0f);

        float zz[NL];
        #pragma unroll
        for (int m = 0; m < NL; ++m) zz[m] = s_bl[m];
        #pragma unroll
        for (int l = 0; l < NL; ++l) {
            #pragma unroll
            for (int m = 0; m < NL; ++m)
                zz[m] = fmaf(h1[l], s_Wl[l * NL + m], zz[m]);
        }
        #pragma unroll
        for (int m = 0; m < NL; ++m) zz[m] = fmaxf(zz[m], 0.0f);

        float d0[NH];
        #pragma unroll
        for (int h = 0; h < NH; ++h) d0[h] = s_bd0[h];
        #pragma unroll
        for (int l = 0; l < NL; ++l) {
            #pragma unroll
            for (int h = 0; h < NH; ++h)
                d0[h] = fmaf(zz[l], s_Wd0[l * NH + h], d0[h]);
        }
        // no ReLU on d0

        float d1[NF];
        #pragma unroll
        for (int f = 0; f < NF; ++f) d1[f] = s_bd1[f];
        #pragma unroll
        for (int h = 0; h < NH; ++h) {
            #pragma unroll
            for (int f = 0; f < NF; ++f)
                d1[f] = fmaf(d0[h], s_Wd1[h * NF + f], d1[f]);
        }

        const int t = tid >> 4, r16 = tid & 15;
        #pragma unroll
        for (int kc = 0; kc < 4; ++kc) {
            half8 v;
            #pragma unroll
            for (int j = 0; j < 8; ++j)
                v[j] = (_Float16)fmaxf(d1[kc * 8 + j], 0.0f);   // relu on d1
            const int u = (t * 4 + kc) * 16 + r16;
            *reinterpret_cast<half8*>(&sA[u * 8]) = v;
        }
    }
    __syncthreads();

    // ---- phase 2: frags -> registers, then the pool is repack space ----
    const int w   = tid >> 6;     // wave id: row-tiles [4w, 4w+4)
    const int l   = tid & 63;
    const int r16 = l & 15;       // output row within tile
    const int cq  = (l >> 4) * 4; // output col quad base within col-tile

    half8 bfr[16];
    #pragma unroll
    for (int ct = 0; ct < 16; ++ct)
        bfr[ct] = *reinterpret_cast<const half8*>(&sB[(ct * 64 + l) * 8]);
    half8 afr[4];
    #pragma unroll
    for (int i = 0; i < 4; ++i)
        afr[i] = *reinterpret_cast<const half8*>(&sA[((w * 4 + i) * 64 + l) * 8]);

    __syncthreads();   // frags in registers everywhere; pool free for repack

    // ---- row-pipelined: store tile i-1 rows interleaved with tile i compute ----
    {
        float* rep = &sPool[w * 16 * S_REP];   // this wave's 16x256 tile (padded)
        const long orow0 = (long)e * NB + b0 + w * 64;   // first row of this wave

        // one ct-quad of tile i: MFMA + sigmoid + LDS scatter (no vmem!)
        #define COMPUTE_CT(i_, ct_)                                                     \
        {                                                                               \
            floatx4 acc = *reinterpret_cast<const floatx4*>(&sBias[(ct_) * 16 + cq]);   \
            acc = __builtin_amdgcn_mfma_f32_16x16x32_f16(bfr[(ct_)], afr[(i_)], acc, 0, 0, 0); \
            floatx4 o;                                                                  \
            o.x = sig2(acc[0]);                                                         \
            o.y = sig2(acc[1]);                                                         \
            o.z = sig2(acc[2]);                                                         \
            o.w = sig2(acc[3]);                                                         \
            *reinterpret_cast<floatx4*>(&rep[r16 * S_REP + (ct_) * 16 + cq]) = o;       \
        }

        // prologue: compute tile 0, pull its 16 rows into VGPRs
        #pragma unroll
        for (int ct = 0; ct < 16; ++ct) COMPUTE_CT(0, ct)
        floatx4 rows[16];
        #pragma unroll
        for (int r = 0; r < 16; ++r)
            rows[r] = *reinterpret_cast<const floatx4*>(&rep[r * S_REP + 4 * l]);

        #pragma unroll
        for (int i = 1; i < 4; ++i) {
            float* obase = out + (orow0 + (long)(i - 1) * 16) * ND + 4 * l;
            #pragma unroll
            for (int r = 0; r < 16; ++r) {
                // 1KB full-row NT store of tile i-1 row r ...
                __builtin_nontemporal_store(rows[r],
                    reinterpret_cast<floatx4*>(obase + (long)r * ND));
                // ... followed by ~20 compute instructions of tile i
                COMPUTE_CT(i, r)
            }
            #pragma unroll
            for (int r = 0; r < 16; ++r)
                rows[r] = *reinterpret_cast<const floatx4*>(&rep[r * S_REP + 4 * l]);
        }
        // epilogue: store tile 3
        {
            float* obase = out + (orow0 + 48) * ND + 4 * l;
            #pragma unroll
            for (int r = 0; r < 16; ++r)
                __builtin_nontemporal_store(rows[r],
                    reinterpret_cast<floatx4*>(obase + (long)r * ND));
        }
        #undef COMPUTE_CT
    }
}

extern "C" void kernel_launch(void* const* d_in, const int* in_sizes, int n_in,
                              void* d_out, int out_size, void* d_ws, size_t ws_size,
                              hipStream_t stream) {
    const float* x   = (const float*)d_in[0];
    const int*   idx = (const int*)  d_in[1];
    const float* We0 = (const float*)d_in[2];
    const float* be0 = (const float*)d_in[3];
    const float* We1 = (const float*)d_in[4];
    const float* be1 = (const float*)d_in[5];
    const float* Wl  = (const float*)d_in[6];
    const float* bl  = (const float*)d_in[7];
    const float* Wd0 = (const float*)d_in[8];
    const float* bd0 = (const float*)d_in[9];
    const float* Wd1 = (const float*)d_in[10];
    const float* bd1 = (const float*)d_in[11];
    const float* Wo  = (const float*)d_in[12];
    const float* bo  = (const float*)d_in[13];
    float* out = (float*)d_out;

    dim3 grid(NB / BT, NE);
    dim3 block(256);
    hipLaunchKernelGGL(bagae_mfma, grid, block, 0, stream,
                       x, idx, We0, be0, We1, be1, Wl, bl,
                       Wd0, bd0, Wd1, bd1, Wo, bo, out);
}